// Round 1
// baseline (556.859 us; speedup 1.0000x reference)
//
#include <hip/hip_runtime.h>

// Problem constants (from reference setup_inputs)
#define B_   4
#define T_   1024
#define E_   4
#define C_   512
#define IN_  2048
#define OUT_ 8192
#define EI_  512   // expert in-features = IN_/E_

typedef float f32x4 __attribute__((ext_vector_type(4)));
typedef __bf16 bf16x8 __attribute__((ext_vector_type(8)));
typedef unsigned short ushort8 __attribute__((ext_vector_type(8)));

__device__ __forceinline__ unsigned short f32_bf16(float f) {
  unsigned int u = __float_as_uint(f);
  u += 0x7FFFu + ((u >> 16) & 1u);   // round-to-nearest-even (finite inputs)
  return (unsigned short)(u >> 16);
}

__device__ __forceinline__ unsigned int pack2(float lo, float hi) {
  return (unsigned int)f32_bf16(lo) | ((unsigned int)f32_bf16(hi) << 16);
}

__device__ __forceinline__ void gl2lds16(const void* g, void* l) {
  __builtin_amdgcn_global_load_lds(
      (const __attribute__((address_space(1))) void*)g,
      (__attribute__((address_space(3))) void*)l, 16, 0, 0);
}

// ---------------------------------------------------------------------------
// fp32 -> bf16 elementwise convert, 8 elems/thread (2x float4 load, 16B store)
// ---------------------------------------------------------------------------
__global__ void cvt_f32_to_bf16(const float* __restrict__ in,
                                unsigned short* __restrict__ out, int n8) {
  int i = blockIdx.x * 256 + threadIdx.x;
  if (i >= n8) return;
  const float4* p = (const float4*)in + (size_t)i * 2;
  float4 a = p[0], b = p[1];
  ushort8 r;
  r[0] = f32_bf16(a.x); r[1] = f32_bf16(a.y);
  r[2] = f32_bf16(a.z); r[3] = f32_bf16(a.w);
  r[4] = f32_bf16(b.x); r[5] = f32_bf16(b.y);
  r[6] = f32_bf16(b.z); r[7] = f32_bf16(b.w);
  *((ushort8*)out + i) = r;
}

// ---------------------------------------------------------------------------
// GEMM1 (TN): xd[b,e,c,k] = sum_t mask[b,t,e,c] * x[b,t,e*512+k]
// Both operands are t(K)-strided in memory -> VGPR-staged transpose into LDS
// with fp32->bf16 inline convert. LDS rows padded to LDK=40 (80B, 16B-aligned)
// to spread staging-write bank conflicts while keeping ds_read_b128 frags.
// Tiny GEMM (8.6 GF, 256 blocks = 1/CU) so staging cost is acceptable.
// ---------------------------------------------------------------------------
#define LDK 40

__global__ __launch_bounds__(256, 2)
void gemm_tn(const float* __restrict__ mask, const float* __restrict__ x,
             unsigned short* __restrict__ xd) {
  __shared__ __align__(16) unsigned short As[128 * LDK];
  __shared__ __align__(16) unsigned short Bs[128 * LDK];
  const int u = threadIdx.x;
  const int z = blockIdx.z;          // b*E + e
  const int b = z >> 2, e = z & 3;
  const int m0 = blockIdx.y * 128;   // c tile
  const int n0 = blockIdx.x * 128;   // k tile

  // mask flat: b*T*E*C + t*(E*C) + e*C + c   (t-stride 2048 elems)
  // x    flat: b*T*IN  + t*IN    + e*EI + k  (t-stride 2048 elems)
  const float* maskB = mask + (long)b * 2097152 + e * C_ + m0;
  const float* xB    = x    + (long)b * 2097152 + e * EI_ + n0;

  const int cgl = u & 31;   // c/k group of 4 (lanes contiguous -> coalesced)
  const int tp0 = u >> 5;   // 0..7 (t-pair), second unit adds 8

  const int w = u >> 6, lane = u & 63;
  const int wm = (w & 1) * 64, wn = (w >> 1) * 64;
  const int fm = lane & 15, fk = (lane >> 4) * 8;

  f32x4 acc[4][4] = {};

  for (int kt = 0; kt < T_; kt += 32) {
    __syncthreads();
#pragma unroll
    for (int un = 0; un < 2; un++) {
      const int tp = tp0 + un * 8;
      const int t = kt + tp * 2;
      const float* ga = maskB + (long)t * 2048 + cgl * 4;
      float4 a0 = *(const float4*)ga;
      float4 a1 = *(const float4*)(ga + 2048);
      const float* gb = xB + (long)t * 2048 + cgl * 4;
      float4 b0 = *(const float4*)gb;
      float4 b1 = *(const float4*)(gb + 2048);
      // transpose into [m][t] rows: pack (t, t+1) pair -> one b32 write
      *(unsigned int*)&As[(cgl * 4 + 0) * LDK + tp * 2] = pack2(a0.x, a1.x);
      *(unsigned int*)&As[(cgl * 4 + 1) * LDK + tp * 2] = pack2(a0.y, a1.y);
      *(unsigned int*)&As[(cgl * 4 + 2) * LDK + tp * 2] = pack2(a0.z, a1.z);
      *(unsigned int*)&As[(cgl * 4 + 3) * LDK + tp * 2] = pack2(a0.w, a1.w);
      *(unsigned int*)&Bs[(cgl * 4 + 0) * LDK + tp * 2] = pack2(b0.x, b1.x);
      *(unsigned int*)&Bs[(cgl * 4 + 1) * LDK + tp * 2] = pack2(b0.y, b1.y);
      *(unsigned int*)&Bs[(cgl * 4 + 2) * LDK + tp * 2] = pack2(b0.z, b1.z);
      *(unsigned int*)&Bs[(cgl * 4 + 3) * LDK + tp * 2] = pack2(b0.w, b1.w);
    }
    __syncthreads();
    bf16x8 af[4], bfv[4];
#pragma unroll
    for (int i = 0; i < 4; i++) {
      af[i]  = *(const bf16x8*)&As[(wm + i * 16 + fm) * LDK + fk];
      bfv[i] = *(const bf16x8*)&Bs[(wn + i * 16 + fm) * LDK + fk];
    }
#pragma unroll
    for (int i = 0; i < 4; i++)
#pragma unroll
      for (int j = 0; j < 4; j++)
        acc[i][j] = __builtin_amdgcn_mfma_f32_16x16x32_bf16(af[i], bfv[j],
                                                            acc[i][j], 0, 0, 0);
  }

  // C/D layout: col = lane&15, row = (lane>>4)*4 + reg  [measured m89/m91]
  unsigned short* outB = xd + (long)z * 262144;  // (b,e) slice, rows c stride 512
  const int rm = wm + ((lane >> 4) << 2);
  const int rn = wn + (lane & 15);
#pragma unroll
  for (int i = 0; i < 4; i++)
#pragma unroll
    for (int r = 0; r < 4; r++) {
      const int m = m0 + rm + i * 16 + r;
#pragma unroll
      for (int j = 0; j < 4; j++)
        outB[(long)m * EI_ + n0 + rn + j * 16] = f32_bf16(acc[i][j][r]);
    }
}

// ---------------------------------------------------------------------------
// gemm_bt (m97 structure): D[m,n] = sum_k A[m,k]*B[n,k] (+bias[m])
// Both operands row-major along K -> 16B global_load_lds staging, 128x128
// tile, BK=32, 4 waves of 4x4 16x16x32 bf16 MFMA fragments.
// Per-z operand offsets: off = (z/Ediv)*s?b + (z%Ediv)*s?e.
// ---------------------------------------------------------------------------
template <bool ADD_BIAS, bool OUT_F32>
__global__ __launch_bounds__(256, 2)
void gemm_bt(const unsigned short* __restrict__ A,
             const unsigned short* __restrict__ Bm,
             void* __restrict__ Out, const float* __restrict__ bias,
             int lda, int ldb, int ldo, int K, int Ediv,
             long sAb, long sAe, long sBb, long sBe, long sOb, long sOe) {
  __shared__ __align__(16) unsigned short As[128 * 32];
  __shared__ __align__(16) unsigned short Bs[128 * 32];
  const int u = threadIdx.x;
  const int z = blockIdx.z;
  const int zb = z / Ediv, ze = z % Ediv;
  const unsigned short* Ab = A  + zb * sAb + ze * sAe + (long)(blockIdx.y * 128) * lda;
  const unsigned short* Bb = Bm + zb * sBb + ze * sBe + (long)(blockIdx.x * 128) * ldb;

  // staging: 4 lanes per 64B row; inst0 rows 0-63, inst1 rows 64-127
  const int srow = u >> 2;
  const int scol = (u & 3) * 8;
  const unsigned short* ga0 = Ab + (long)srow * lda + scol;
  const unsigned short* ga1 = ga0 + (long)64 * lda;
  const unsigned short* gb0 = Bb + (long)srow * ldb + scol;
  const unsigned short* gb1 = gb0 + (long)64 * ldb;

  const int w = u >> 6, lane = u & 63;
  unsigned short* la0 = As + w * 512;   // wave-uniform base + lane*16 == u*16B
  unsigned short* la1 = la0 + 2048;
  unsigned short* lb0 = Bs + w * 512;
  unsigned short* lb1 = lb0 + 2048;

  const int wm = (w & 1) * 64, wn = (w >> 1) * 64;
  const int fm = lane & 15, fk = (lane >> 4) * 8;
  const unsigned short* pA = As + (wm + fm) * 32 + fk;
  const unsigned short* pB = Bs + (wn + fm) * 32 + fk;

  f32x4 acc[4][4] = {};

  for (int kt = 0; kt < K; kt += 32) {
    __syncthreads();
    gl2lds16(ga0, la0);
    gl2lds16(ga1, la1);
    gl2lds16(gb0, lb0);
    gl2lds16(gb1, lb1);
    ga0 += 32; ga1 += 32; gb0 += 32; gb1 += 32;
    __syncthreads();
    bf16x8 af[4], bfv[4];
#pragma unroll
    for (int i = 0; i < 4; i++) {
      af[i]  = *(const bf16x8*)(pA + i * 16 * 32);
      bfv[i] = *(const bf16x8*)(pB + i * 16 * 32);
    }
#pragma unroll
    for (int i = 0; i < 4; i++)
#pragma unroll
      for (int j = 0; j < 4; j++)
        acc[i][j] = __builtin_amdgcn_mfma_f32_16x16x32_bf16(af[i], bfv[j],
                                                            acc[i][j], 0, 0, 0);
  }

  const long ob = zb * sOb + ze * sOe;
  const int em0 = blockIdx.y * 128 + wm + ((lane >> 4) << 2);
  const int en0 = blockIdx.x * 128 + wn + (lane & 15);
#pragma unroll
  for (int i = 0; i < 4; i++)
#pragma unroll
    for (int r = 0; r < 4; r++) {
      const int m = em0 + i * 16 + r;
      const float bv = ADD_BIAS ? bias[m] : 0.0f;
#pragma unroll
      for (int j = 0; j < 4; j++) {
        const float v = acc[i][j][r] + bv;
        const long off = ob + (long)m * ldo + en0 + j * 16;
        if (OUT_F32)
          ((float*)Out)[off] = v;
        else
          ((unsigned short*)Out)[off] = f32_bf16(v);
      }
    }
}

// ---------------------------------------------------------------------------
// launch
// ---------------------------------------------------------------------------
extern "C" void kernel_launch(void* const* d_in, const int* in_sizes, int n_in,
                              void* d_out, int out_size, void* d_ws,
                              size_t ws_size, hipStream_t stream) {
  (void)in_sizes; (void)n_in; (void)out_size; (void)ws_size;
  const float* x       = (const float*)d_in[0];  // (B,T,IN)
  const float* combine = (const float*)d_in[1];  // (B,T,E,C)
  const float* mask    = (const float*)d_in[2];  // (B,T,E,C)
  const float* weight  = (const float*)d_in[3];  // (OUT,IN)
  const float* bias    = (const float*)d_in[4];  // (OUT,)
  float* out = (float*)d_out;                    // (B,T,OUT) fp32

  // workspace: 185 MB total
  char* ws = (char*)d_ws;
  unsigned short* w_bf    = (unsigned short*)ws;                    // 16M el, 32 MB
  unsigned short* comb_bf = (unsigned short*)(ws + 33554432);       // 8M el, 16 MB
  unsigned short* xd      = (unsigned short*)(ws + 50331648);       // 4M el,  8 MB
  unsigned short* yT      = (unsigned short*)(ws + 58720256);       // 64M el, 128 MB

  // 0) convert weight + combine to bf16 (x/mask converted inline in gemm_tn)
  cvt_f32_to_bf16<<<8192, 256, 0, stream>>>(weight, w_bf, 16777216 / 8);
  cvt_f32_to_bf16<<<4096, 256, 0, stream>>>(combine, comb_bf, 8388608 / 8);

  // 1) xd[b,e,c,k] (bf16), grid: 4 k-tiles x 4 c-tiles x 16 (b,e)
  gemm_tn<<<dim3(4, 4, 16), 256, 0, stream>>>(mask, x, xd);

  // 2) yT[b,o,e,c] = w[e,o,:] . xd[b,e,c,:] + bias[o]
  //    M=O(8192) N=C(512) K=512; A=w_bf (lda 512), B=xd (ldb 512), ldo=E*C
  gemm_bt<true, false><<<dim3(4, 64, 16), 256, 0, stream>>>(
      w_bf, xd, (void*)yT, bias, 512, 512, 2048, 512,
      4, 0L, 4194304L, 1048576L, 262144L, 16777216L, 512L);

  // 3) out[b,t,o] = combine[b,t,:] . yT[b,o,:]
  //    M=T(1024) N=O(8192) K=E*C(2048); A=comb_bf, B=yT, fp32 out
  gemm_bt<false, true><<<dim3(64, 8, 4), 256, 0, stream>>>(
      comb_bf, yT, (void*)out, nullptr, 2048, 2048, 8192, 2048,
      1, 2097152L, 0L, 16777216L, 0L, 8388608L, 0L);
}

// Round 2
// 547.912 us; speedup vs baseline: 1.0163x; 1.0163x over previous
//
#include <hip/hip_runtime.h>

// Problem constants (from reference setup_inputs)
#define B_   4
#define T_   1024
#define E_   4
#define C_   512
#define IN_  2048
#define OUT_ 8192
#define EI_  512   // expert in-features = IN_/E_

typedef float f32x4 __attribute__((ext_vector_type(4)));
typedef __bf16 bf16x8 __attribute__((ext_vector_type(8)));
typedef unsigned short ushort8 __attribute__((ext_vector_type(8)));

__device__ __forceinline__ unsigned short f32_bf16(float f) {
  unsigned int u = __float_as_uint(f);
  u += 0x7FFFu + ((u >> 16) & 1u);   // round-to-nearest-even (finite inputs)
  return (unsigned short)(u >> 16);
}

__device__ __forceinline__ void gl2lds16(const void* g, void* l) {
  __builtin_amdgcn_global_load_lds(
      (const __attribute__((address_space(1))) void*)g,
      (__attribute__((address_space(3))) void*)l, 16, 0, 0);
}

// ---------------------------------------------------------------------------
// fp32 -> bf16 elementwise convert, 8 elems/thread (2x float4 load, 16B store)
// ---------------------------------------------------------------------------
__global__ void cvt_f32_to_bf16(const float* __restrict__ in,
                                unsigned short* __restrict__ out, int n8) {
  int i = blockIdx.x * 256 + threadIdx.x;
  if (i >= n8) return;
  const float4* p = (const float4*)in + (size_t)i * 2;
  float4 a = p[0], b = p[1];
  ushort8 r;
  r[0] = f32_bf16(a.x); r[1] = f32_bf16(a.y);
  r[2] = f32_bf16(a.z); r[3] = f32_bf16(a.w);
  r[4] = f32_bf16(b.x); r[5] = f32_bf16(b.y);
  r[6] = f32_bf16(b.z); r[7] = f32_bf16(b.w);
  *((ushort8*)out + i) = r;
}

// ---------------------------------------------------------------------------
// Transpose-convert: src (B, T, 2048) fp32  ->  dst (B, E=4, 512, T) bf16.
// Inner 2048 decodes as e*512 + kl for BOTH x (e*EI+k) and mask (e*C+c),
// so one kernel serves both operands. 64x64 tiles via padded fp32 LDS.
// Read phase: lanes span k (consecutive LDS addrs -> 2 lanes/bank = free).
// ---------------------------------------------------------------------------
__global__ __launch_bounds__(256)
void transpose_cvt(const float* __restrict__ src, unsigned short* __restrict__ dst) {
  __shared__ float tile[64][68];   // pad 68: row stride 272B, 16B-aligned
  const int b = blockIdx.z;
  const int k0 = blockIdx.x * 64;
  const int t0 = blockIdx.y * 64;
  const int u = threadIdx.x;
  // load 64 t-rows x 64 k-cols fp32, coalesced float4
  const int lrow = u >> 4;          // 0..15
  const int lcol = (u & 15) * 4;
  const float* s = src + (size_t)b * (T_ * 2048) + (size_t)t0 * 2048 + k0;
#pragma unroll
  for (int r = 0; r < 4; r++) {
    float4 v = *(const float4*)(s + (size_t)(lrow + 16 * r) * 2048 + lcol);
    tile[lrow + 16 * r][lcol]     = v.x;
    tile[lrow + 16 * r][lcol + 1] = v.y;
    tile[lrow + 16 * r][lcol + 2] = v.z;
    tile[lrow + 16 * r][lcol + 3] = v.w;
  }
  __syncthreads();
  // write: lane = k row (0..63), each wave covers 16 t as 2x ushort8 stores
  const int w = u >> 6, lane = u & 63;
  const int kg = k0 + lane;
  const int e  = kg >> 9;
  const int kl = kg & 511;
  unsigned short* d = dst + (((size_t)b * 4 + e) * 512 + kl) * 1024 + t0 + w * 16;
#pragma unroll
  for (int s8 = 0; s8 < 2; s8++) {
    const int tt = w * 16 + s8 * 8;
    ushort8 r;
#pragma unroll
    for (int j = 0; j < 8; j++) r[j] = f32_bf16(tile[tt + j][lane]);
    *(ushort8*)(d + s8 * 8) = r;
  }
}

// ---------------------------------------------------------------------------
// gemm_bt (m97 structure): D[m,n] = sum_k A[m,k]*B[n,k] (+bias[m])
// Both operands row-major along K -> 16B global_load_lds staging, 128x128
// tile, BK=32, 4 waves of 4x4 16x16x32 bf16 MFMA fragments.
// Per-z operand offsets: off = (z/Ediv)*s?b + (z%Ediv)*s?e.
// ---------------------------------------------------------------------------
template <bool ADD_BIAS, bool OUT_F32>
__global__ __launch_bounds__(256, 2)
void gemm_bt(const unsigned short* __restrict__ A,
             const unsigned short* __restrict__ Bm,
             void* __restrict__ Out, const float* __restrict__ bias,
             int lda, int ldb, int ldo, int K, int Ediv,
             long sAb, long sAe, long sBb, long sBe, long sOb, long sOe) {
  __shared__ __align__(16) unsigned short As[128 * 32];
  __shared__ __align__(16) unsigned short Bs[128 * 32];
  const int u = threadIdx.x;
  const int z = blockIdx.z;
  const int zb = z / Ediv, ze = z % Ediv;
  const unsigned short* Ab = A  + zb * sAb + ze * sAe + (long)(blockIdx.y * 128) * lda;
  const unsigned short* Bb = Bm + zb * sBb + ze * sBe + (long)(blockIdx.x * 128) * ldb;

  // staging: 4 lanes per 64B row; inst0 rows 0-63, inst1 rows 64-127
  const int srow = u >> 2;
  const int scol = (u & 3) * 8;
  const unsigned short* ga0 = Ab + (long)srow * lda + scol;
  const unsigned short* ga1 = ga0 + (long)64 * lda;
  const unsigned short* gb0 = Bb + (long)srow * ldb + scol;
  const unsigned short* gb1 = gb0 + (long)64 * ldb;

  const int w = u >> 6, lane = u & 63;
  unsigned short* la0 = As + w * 512;   // wave-uniform base + lane*16 == u*16B
  unsigned short* la1 = la0 + 2048;
  unsigned short* lb0 = Bs + w * 512;
  unsigned short* lb1 = lb0 + 2048;

  const int wm = (w & 1) * 64, wn = (w >> 1) * 64;
  const int fm = lane & 15, fk = (lane >> 4) * 8;
  const unsigned short* pA = As + (wm + fm) * 32 + fk;
  const unsigned short* pB = Bs + (wn + fm) * 32 + fk;

  f32x4 acc[4][4] = {};

  for (int kt = 0; kt < K; kt += 32) {
    __syncthreads();
    gl2lds16(ga0, la0);
    gl2lds16(ga1, la1);
    gl2lds16(gb0, lb0);
    gl2lds16(gb1, lb1);
    ga0 += 32; ga1 += 32; gb0 += 32; gb1 += 32;
    __syncthreads();
    bf16x8 af[4], bfv[4];
#pragma unroll
    for (int i = 0; i < 4; i++) {
      af[i]  = *(const bf16x8*)(pA + i * 16 * 32);
      bfv[i] = *(const bf16x8*)(pB + i * 16 * 32);
    }
#pragma unroll
    for (int i = 0; i < 4; i++)
#pragma unroll
      for (int j = 0; j < 4; j++)
        acc[i][j] = __builtin_amdgcn_mfma_f32_16x16x32_bf16(af[i], bfv[j],
                                                            acc[i][j], 0, 0, 0);
  }

  // C/D layout: col = lane&15, row = (lane>>4)*4 + reg  [measured m89/m91]
  const long ob = zb * sOb + ze * sOe;
  const int em0 = blockIdx.y * 128 + wm + ((lane >> 4) << 2);
  const int en0 = blockIdx.x * 128 + wn + (lane & 15);
#pragma unroll
  for (int i = 0; i < 4; i++)
#pragma unroll
    for (int r = 0; r < 4; r++) {
      const int m = em0 + i * 16 + r;
      const float bv = ADD_BIAS ? bias[m] : 0.0f;
#pragma unroll
      for (int j = 0; j < 4; j++) {
        const float v = acc[i][j][r] + bv;
        const long off = ob + (long)m * ldo + en0 + j * 16;
        if (OUT_F32)
          ((float*)Out)[off] = v;
        else
          ((unsigned short*)Out)[off] = f32_bf16(v);
      }
    }
}

// ---------------------------------------------------------------------------
// launch
// ---------------------------------------------------------------------------
extern "C" void kernel_launch(void* const* d_in, const int* in_sizes, int n_in,
                              void* d_out, int out_size, void* d_ws,
                              size_t ws_size, hipStream_t stream) {
  (void)in_sizes; (void)n_in; (void)out_size; (void)ws_size;
  const float* x       = (const float*)d_in[0];  // (B,T,IN)
  const float* combine = (const float*)d_in[1];  // (B,T,E,C)
  const float* mask    = (const float*)d_in[2];  // (B,T,E,C)
  const float* weight  = (const float*)d_in[3];  // (OUT,IN)
  const float* bias    = (const float*)d_in[4];  // (OUT,)
  float* out = (float*)d_out;                    // (B,T,OUT) fp32

  // workspace layout (184 MB peak; xT/maskT alias the yT region -- they are
  // dead after gemm1, and GEMM2 which writes yT is stream-ordered after it)
  char* ws = (char*)d_ws;
  unsigned short* w_bf    = (unsigned short*)ws;                    // 32 MB
  unsigned short* comb_bf = (unsigned short*)(ws + 33554432);       // 16 MB
  unsigned short* xd      = (unsigned short*)(ws + 50331648);       //  8 MB
  unsigned short* yT      = (unsigned short*)(ws + 58720256);       // 128 MB
  unsigned short* xT      = (unsigned short*)(ws + 58720256);       // 16 MB (alias)
  unsigned short* maskT   = (unsigned short*)(ws + 75497472);       // 16 MB (alias)

  // 0) transpose-convert x -> xT[b,e,k,t], mask -> maskT[b,e,c,t]
  transpose_cvt<<<dim3(32, 16, 4), 256, 0, stream>>>(x, xT);
  transpose_cvt<<<dim3(32, 16, 4), 256, 0, stream>>>(mask, maskT);

  // 0b) convert weight + combine to bf16
  cvt_f32_to_bf16<<<8192, 256, 0, stream>>>(weight, w_bf, 16777216 / 8);
  cvt_f32_to_bf16<<<4096, 256, 0, stream>>>(combine, comb_bf, 8388608 / 8);

  // 1) xd[b,e,c,k] = sum_t maskT[b,e,c,t] * xT[b,e,k,t]
  //    M=C(512) N=EI(512) K=T(1024); lda=ldb=1024, ldo=512
  gemm_bt<false, false><<<dim3(4, 4, 16), 256, 0, stream>>>(
      maskT, xT, (void*)xd, nullptr, 1024, 1024, 512, 1024,
      4, 2097152L, 524288L, 2097152L, 524288L, 1048576L, 262144L);

  // 2) yT[b,o,e,c] = w[e,o,:] . xd[b,e,c,:] + bias[o]
  //    M=O(8192) N=C(512) K=512; A=w_bf (lda 512), B=xd (ldb 512), ldo=E*C
  gemm_bt<true, false><<<dim3(4, 64, 16), 256, 0, stream>>>(
      w_bf, xd, (void*)yT, bias, 512, 512, 2048, 512,
      4, 0L, 4194304L, 1048576L, 262144L, 16777216L, 512L);

  // 3) out[b,t,o] = combine[b,t,:] . yT[b,o,:]
  //    M=T(1024) N=O(8192) K=E*C(2048); A=comb_bf, B=yT, fp32 out
  gemm_bt<false, true><<<dim3(64, 8, 4), 256, 0, stream>>>(
      comb_bf, yT, (void*)out, nullptr, 2048, 2048, 8192, 2048,
      1, 2097152L, 0L, 16777216L, 0L, 8388608L, 0L);
}

// Round 3
// 453.071 us; speedup vs baseline: 1.2291x; 1.2093x over previous
//
#include <hip/hip_runtime.h>

// Problem constants (from reference setup_inputs)
#define B_   4
#define T_   1024
#define E_   4
#define C_   512
#define IN_  2048
#define OUT_ 8192
#define EI_  512   // expert in-features = IN_/E_

typedef float f32x4 __attribute__((ext_vector_type(4)));
typedef __bf16 bf16x8 __attribute__((ext_vector_type(8)));
typedef unsigned short ushort8 __attribute__((ext_vector_type(8)));

__device__ __forceinline__ unsigned short f32_bf16(float f) {
  unsigned int u = __float_as_uint(f);
  u += 0x7FFFu + ((u >> 16) & 1u);   // round-to-nearest-even (finite inputs)
  return (unsigned short)(u >> 16);
}

__device__ __forceinline__ void gl2lds16(const void* g, void* l) {
  __builtin_amdgcn_global_load_lds(
      (const __attribute__((address_space(1))) void*)g,
      (__attribute__((address_space(3))) void*)l, 16, 0, 0);
}

// ---------------------------------------------------------------------------
// Transpose-convert: src (B, T, 2048) fp32  ->  dst (B, E=4, 512, T) bf16.
// Inner 2048 decodes as e*512 + kl for BOTH x (e*EI+k) and mask (e*C+c).
// ---------------------------------------------------------------------------
__global__ __launch_bounds__(256)
void transpose_cvt(const float* __restrict__ src, unsigned short* __restrict__ dst) {
  __shared__ float tile[64][68];   // pad 68: row stride 272B, 16B-aligned
  const int b = blockIdx.z;
  const int k0 = blockIdx.x * 64;
  const int t0 = blockIdx.y * 64;
  const int u = threadIdx.x;
  const int lrow = u >> 4;          // 0..15
  const int lcol = (u & 15) * 4;
  const float* s = src + (size_t)b * (T_ * 2048) + (size_t)t0 * 2048 + k0;
#pragma unroll
  for (int r = 0; r < 4; r++) {
    float4 v = *(const float4*)(s + (size_t)(lrow + 16 * r) * 2048 + lcol);
    tile[lrow + 16 * r][lcol]     = v.x;
    tile[lrow + 16 * r][lcol + 1] = v.y;
    tile[lrow + 16 * r][lcol + 2] = v.z;
    tile[lrow + 16 * r][lcol + 3] = v.w;
  }
  __syncthreads();
  const int w = u >> 6, lane = u & 63;
  const int kg = k0 + lane;
  const int e  = kg >> 9;
  const int kl = kg & 511;
  unsigned short* d = dst + (((size_t)b * 4 + e) * 512 + kl) * 1024 + t0 + w * 16;
#pragma unroll
  for (int s8 = 0; s8 < 2; s8++) {
    const int tt = w * 16 + s8 * 8;
    ushort8 r;
#pragma unroll
    for (int j = 0; j < 8; j++) r[j] = f32_bf16(tile[tt + j][lane]);
    *(ushort8*)(d + s8 * 8) = r;
  }
}

// ---------------------------------------------------------------------------
// combine (B,T,E,C) fp32 -> bf16, plus row-sum S[b,t] = sum_{e,c} combine
// One block per (b,t) row of 2048 elements; 8 elems/thread.
// ---------------------------------------------------------------------------
__global__ __launch_bounds__(256)
void cvt_combine_rowsum(const float* __restrict__ in,
                        unsigned short* __restrict__ out,
                        float* __restrict__ S) {
  const int row = blockIdx.x;   // 0..4095  (b*1024 + t)
  const int u = threadIdx.x;
  const float4* p = (const float4*)(in + (size_t)row * 2048) + (size_t)u * 2;
  float4 a = p[0], b = p[1];
  ushort8 r;
  r[0] = f32_bf16(a.x); r[1] = f32_bf16(a.y);
  r[2] = f32_bf16(a.z); r[3] = f32_bf16(a.w);
  r[4] = f32_bf16(b.x); r[5] = f32_bf16(b.y);
  r[6] = f32_bf16(b.z); r[7] = f32_bf16(b.w);
  *((ushort8*)(out + (size_t)row * 2048) + u) = r;
  float s = (a.x + a.y + a.z + a.w) + (b.x + b.y + b.z + b.w);
  __shared__ float red[256];
  red[u] = s;
  __syncthreads();
#pragma unroll
  for (int st = 128; st > 0; st >>= 1) {
    if (u < st) red[u] += red[u + st];
    __syncthreads();
  }
  if (u == 0) S[row] = red[0];
}

// ---------------------------------------------------------------------------
// weight (OUT,IN) fp32, logically w[e,o,i] = weight.flat[e*4194304 + o*512 + i]
//  -> W2 bf16 with W2[o*2048 + e*512 + i]  (K=(e,i) contiguous per o-row)
// ---------------------------------------------------------------------------
__global__ __launch_bounds__(256)
void permute_w(const float* __restrict__ weight, unsigned short* __restrict__ W2) {
  const int tid = blockIdx.x * 256 + threadIdx.x;  // 2,097,152 threads
  const int i8 = tid & 63;
  const int e  = (tid >> 6) & 3;
  const int o  = tid >> 8;
  const float* s = weight + (size_t)e * 4194304 + (size_t)o * 512 + i8 * 8;
  float4 a = *(const float4*)s;
  float4 b = *(const float4*)(s + 4);
  ushort8 r;
  r[0] = f32_bf16(a.x); r[1] = f32_bf16(a.y);
  r[2] = f32_bf16(a.z); r[3] = f32_bf16(a.w);
  r[4] = f32_bf16(b.x); r[5] = f32_bf16(b.y);
  r[6] = f32_bf16(b.z); r[7] = f32_bf16(b.w);
  *(ushort8*)(W2 + (size_t)o * 2048 + e * 512 + i8 * 8) = r;
}

// ---------------------------------------------------------------------------
// gemm_bt (m97 structure): D[m,n] = sum_k A[m,k]*B[n,k]
// MODE 0: store bf16. MODE 1: store fp32, add S[m]*bias[n] (final GEMM).
// Per-z operand offsets: off = (z/Ediv)*s?b + (z%Ediv)*s?e.
// ---------------------------------------------------------------------------
template <int MODE>
__global__ __launch_bounds__(256, 2)
void gemm_bt(const unsigned short* __restrict__ A,
             const unsigned short* __restrict__ Bm,
             void* __restrict__ Out, const float* __restrict__ bias,
             const float* __restrict__ S,
             int lda, int ldb, int ldo, int K, int Ediv,
             long sAb, long sAe, long sBb, long sBe, long sOb, long sOe) {
  __shared__ __align__(16) unsigned short As[128 * 32];
  __shared__ __align__(16) unsigned short Bs[128 * 32];
  const int u = threadIdx.x;
  const int z = blockIdx.z;
  const int zb = z / Ediv, ze = z % Ediv;
  const unsigned short* Ab = A  + zb * sAb + ze * sAe + (long)(blockIdx.y * 128) * lda;
  const unsigned short* Bb = Bm + zb * sBb + ze * sBe + (long)(blockIdx.x * 128) * ldb;

  // staging: 4 lanes per 64B row; inst0 rows 0-63, inst1 rows 64-127
  const int srow = u >> 2;
  const int scol = (u & 3) * 8;
  const unsigned short* ga0 = Ab + (long)srow * lda + scol;
  const unsigned short* ga1 = ga0 + (long)64 * lda;
  const unsigned short* gb0 = Bb + (long)srow * ldb + scol;
  const unsigned short* gb1 = gb0 + (long)64 * ldb;

  const int w = u >> 6, lane = u & 63;
  unsigned short* la0 = As + w * 512;   // wave-uniform base + lane*16 == u*16B
  unsigned short* la1 = la0 + 2048;
  unsigned short* lb0 = Bs + w * 512;
  unsigned short* lb1 = lb0 + 2048;

  const int wm = (w & 1) * 64, wn = (w >> 1) * 64;
  const int fm = lane & 15, fk = (lane >> 4) * 8;
  const unsigned short* pA = As + (wm + fm) * 32 + fk;
  const unsigned short* pB = Bs + (wn + fm) * 32 + fk;

  f32x4 acc[4][4] = {};

  for (int kt = 0; kt < K; kt += 32) {
    __syncthreads();
    gl2lds16(ga0, la0);
    gl2lds16(ga1, la1);
    gl2lds16(gb0, lb0);
    gl2lds16(gb1, lb1);
    ga0 += 32; ga1 += 32; gb0 += 32; gb1 += 32;
    __syncthreads();
    bf16x8 af[4], bfv[4];
#pragma unroll
    for (int i = 0; i < 4; i++) {
      af[i]  = *(const bf16x8*)(pA + i * 16 * 32);
      bfv[i] = *(const bf16x8*)(pB + i * 16 * 32);
    }
#pragma unroll
    for (int i = 0; i < 4; i++)
#pragma unroll
      for (int j = 0; j < 4; j++)
        acc[i][j] = __builtin_amdgcn_mfma_f32_16x16x32_bf16(af[i], bfv[j],
                                                            acc[i][j], 0, 0, 0);
  }

  // C/D layout: col = lane&15, row = (lane>>4)*4 + reg  [measured m89/m91]
  const long ob = zb * sOb + ze * sOe;
  const int em0 = blockIdx.y * 128 + wm + ((lane >> 4) << 2);
  const int en0 = blockIdx.x * 128 + wn + (lane & 15);
  float bcol[4];
  if (MODE == 1) {
#pragma unroll
    for (int j = 0; j < 4; j++) bcol[j] = bias[en0 + j * 16];
  }
#pragma unroll
  for (int i = 0; i < 4; i++)
#pragma unroll
    for (int r = 0; r < 4; r++) {
      const int m = em0 + i * 16 + r;
      const float sm = (MODE == 1) ? S[m] : 0.0f;
#pragma unroll
      for (int j = 0; j < 4; j++) {
        const long off = ob + (long)m * ldo + en0 + j * 16;
        if (MODE == 1)
          ((float*)Out)[off] = acc[i][j][r] + sm * bcol[j];
        else
          ((unsigned short*)Out)[off] = f32_bf16(acc[i][j][r]);
      }
    }
}

// ---------------------------------------------------------------------------
// launch
// ---------------------------------------------------------------------------
extern "C" void kernel_launch(void* const* d_in, const int* in_sizes, int n_in,
                              void* d_out, int out_size, void* d_ws,
                              size_t ws_size, hipStream_t stream) {
  (void)in_sizes; (void)n_in; (void)out_size; (void)ws_size;
  const float* x       = (const float*)d_in[0];  // (B,T,IN)
  const float* combine = (const float*)d_in[1];  // (B,T,E,C)
  const float* mask    = (const float*)d_in[2];  // (B,T,E,C)
  const float* weight  = (const float*)d_in[3];  // (OUT,IN)
  const float* bias    = (const float*)d_in[4];  // (OUT,)
  float* out = (float*)d_out;                    // (B,T,OUT) fp32

  // workspace layout (~105 MB)
  char* ws = (char*)d_ws;
  unsigned short* W2      = (unsigned short*)ws;                    // 32 MB
  unsigned short* comb_bf = (unsigned short*)(ws + 33554432);       // 16 MB
  float*          S       = (float*)(ws + 50331648);                // 16 KB
  unsigned short* xT      = (unsigned short*)(ws + 51380224);       // 16 MB
  unsigned short* maskT   = (unsigned short*)(ws + 68157440);       // 16 MB
  unsigned short* xdT     = (unsigned short*)(ws + 84934656);       //  8 MB
  unsigned short* zbuf    = (unsigned short*)(ws + 93323264);       // 16 MB

  // 0) layout/dtype prep
  transpose_cvt<<<dim3(32, 16, 4), 256, 0, stream>>>(x, xT);        // xT[b,e,i,t]
  transpose_cvt<<<dim3(32, 16, 4), 256, 0, stream>>>(mask, maskT);  // maskT[b,e,c,t]
  cvt_combine_rowsum<<<4096, 256, 0, stream>>>(combine, comb_bf, S);
  permute_w<<<8192, 256, 0, stream>>>(weight, W2);                  // W2[o,(e,i)]

  // 1) xdT[b,e,i,c] = sum_t xT[b,e,i,t] * maskT[b,e,c,t]
  //    M=i(512) N=c(512) K=t(1024)
  gemm_bt<0><<<dim3(4, 4, 16), 256, 0, stream>>>(
      xT, maskT, (void*)xdT, nullptr, nullptr, 1024, 1024, 512, 1024,
      4, 2097152L, 524288L, 2097152L, 524288L, 1048576L, 262144L);

  // 2) z[b,t,(e,i)] = sum_c comb_bf[b,t,e,c] * xdT[b,e,i,c]
  //    M=t(1024) N=i(512) K=c(512), per (b,e)
  gemm_bt<0><<<dim3(4, 8, 16), 256, 0, stream>>>(
      comb_bf, xdT, (void*)zbuf, nullptr, nullptr, 2048, 512, 2048, 512,
      4, 2097152L, 512L, 1048576L, 262144L, 2097152L, 512L);

  // 3) out[m,o] = sum_{(e,i)} z[m,(e,i)] * W2[o,(e,i)] + S[m]*bias[o]
  //    M=4096 N=8192 K=2048, single batch
  gemm_bt<1><<<dim3(64, 32, 1), 256, 0, stream>>>(
      zbuf, W2, (void*)out, bias, S, 2048, 2048, 8192, 2048,
      1, 0L, 0L, 0L, 0L, 0L, 0L);
}